// Round 1
// baseline (295.899 us; speedup 1.0000x reference)
//
#include <hip/hip_runtime.h>
#include <stdint.h>

// Problem constants (fixed by the reference)
#define E_EXPERTS 8
#define D_DIM 1024
#define I_DIM 2048
#define T_TOKENS 4096
#define NSLOTS 8192                 // T * K
#define TILE 128
#define MAXPAD (NSLOTS + E_EXPERTS * TILE)   // 9216
#define TPX 9                       // tiles per XCD chunk (8*9=72 >= max 71 tiles)

// prep grid: 1 routing block + 2048 x-cvt + 2048 w1-transpose + 2048 w2-transpose
#define XCVT_BLOCKS 2048
#define WT_BLOCKS 2048
#define PREP_GRID (1 + XCVT_BLOCKS + 2 * WT_BLOCKS)

typedef __attribute__((ext_vector_type(8))) short bf16x8;
typedef __attribute__((ext_vector_type(4))) float f32x4;

__device__ __forceinline__ unsigned short f2b(float f) {
  union { float f; uint32_t u; } v; v.f = f;
  uint32_t r = v.u + 0x7FFFu + ((v.u >> 16) & 1u);   // round-to-nearest-even
  return (unsigned short)(r >> 16);
}
__device__ __forceinline__ float b2f(unsigned short u) {
  union { uint32_t u; float f; } v; v.u = ((uint32_t)u) << 16; return v.f;
}

// async 16B global -> LDS (dest = wave-uniform base + lane*16)
__device__ __forceinline__ void async16(const unsigned short* g, unsigned short* l) {
  __builtin_amdgcn_global_load_lds(
      (const __attribute__((address_space(1))) void*)g,
      (__attribute__((address_space(3))) void*)l, 16, 0, 0);
}

// ---------------- fused prep ----------------
// block 0                     : routing (count -> scan -> pad-fill + scatter)
// blocks [1, 1+2048)          : x fp32 -> bf16, 8 elems/thread
// blocks [1+2048, 1+2048+2048): w1 [E][D][I] fp32 -> w1t [E][I][D] bf16
// blocks [1+4096, 1+4096+2048): w2 [E][I][D] fp32 -> w2t [E][D][I] bf16
// Transpose is streaming + register-only: each thread owns a 4x8 fp32 subtile,
// 8 float4 loads (wave covers full 128B lines per src row), in-register 4x4
// transpose, 8 ushort4 stores (16 lanes x 8B = 128B contiguous per dst row).
// No LDS, no __syncthreads.
__global__ __launch_bounds__(256) void prep_k(
    const float* __restrict__ x, const float* __restrict__ w1, const float* __restrict__ w2,
    const int* __restrict__ se,
    unsigned short* __restrict__ xb, unsigned short* __restrict__ w1t,
    unsigned short* __restrict__ w2t,
    int* __restrict__ ntiles, int* __restrict__ desc,
    int* __restrict__ tok, int* __restrict__ slot_of) {
  int b = blockIdx.x;
  int tid = threadIdx.x;

  if (b == 0) {
    // ---- single-workgroup routing ----
    __shared__ int scnt[E_EXPERTS], sbase[E_EXPERTS + 1], scur[E_EXPERTS];
    if (tid < E_EXPERTS) scnt[tid] = 0;
    __syncthreads();
    for (int s = tid; s < NSLOTS; s += 256) atomicAdd(&scnt[se[s]], 1);
    __syncthreads();
    if (tid == 0) {
      int acc = 0, nt = 0;
      for (int e = 0; e < E_EXPERTS; e++) {
        int n = scnt[e];
        sbase[e] = acc;
        scur[e] = acc;
        int pad = (n + TILE - 1) & ~(TILE - 1);
        for (int m = 0; m * TILE < pad; m++) { desc[2 * nt] = e; desc[2 * nt + 1] = acc + m * TILE; nt++; }
        acc += pad;
      }
      sbase[E_EXPERTS] = acc;
      *ntiles = nt;
    }
    __syncthreads();
    // pad slots -> token 0 (weight is never read for pads; rows are discarded)
    for (int e = 0; e < E_EXPERTS; e++) {
      int s0 = sbase[e] + scnt[e], s1 = sbase[e + 1];
      for (int s = s0 + tid; s < s1; s += 256) tok[s] = 0;
    }
    // scatter (disjoint from pad range)
    for (int s = tid; s < NSLOTS; s += 256) {
      int e = se[s];
      int pos = atomicAdd(&scur[e], 1);
      tok[pos] = s >> 1;      // K=2
      slot_of[s] = pos;
    }
    return;
  }

  int bb = b - 1;
  int sec = bb >> 11;          // 0: x-cvt, 1: w1, 2: w2
  int sub = bb & 2047;

  if (sec == 0) {
    // ---- x fp32 -> bf16, 8 elems/thread ----
    size_t i = ((size_t)sub * 256 + tid) * 8;
    float4 v0 = *(const float4*)(x + i);
    float4 v1 = *(const float4*)(x + i + 4);
    ushort4 o0, o1;
    o0.x = f2b(v0.x); o0.y = f2b(v0.y); o0.z = f2b(v0.z); o0.w = f2b(v0.w);
    o1.x = f2b(v1.x); o1.y = f2b(v1.y); o1.z = f2b(v1.z); o1.w = f2b(v1.w);
    *(ushort4*)(xb + i) = o0;
    *(ushort4*)(xb + i + 4) = o1;
    return;
  }

  // ---- streaming transpose-cvt: [E][R][C] fp32 -> [E][C][R] bf16 ----
  const float* src; unsigned short* dst; int R, C;
  if (sec == 1) { src = w1; dst = w1t; R = D_DIM; C = I_DIM; }
  else          { src = w2; dst = w2t; R = I_DIM; C = D_DIM; }
  int e = sub >> 8, t = sub & 255;       // 256 (64x128) tiles per expert
  int ctiles = C / 128;                  // 16 (w1) or 8 (w2)
  int r0b = (t / ctiles) * 64, c0b = (t % ctiles) * 128;

  int lane = tid & 63, wave = tid >> 6;
  int c0 = c0b + wave * 32 + (lane >> 4) * 8;   // thread's 8 source cols
  int r0 = r0b + (lane & 15) * 4;               // thread's 4 source rows

  size_t eoff = (size_t)e * R * C;
  const float* s0 = src + eoff + (size_t)r0 * C + c0;

  float4 v[4][2];
#pragma unroll
  for (int i = 0; i < 4; i++) {
    v[i][0] = *(const float4*)(s0 + (size_t)i * C);
    v[i][1] = *(const float4*)(s0 + (size_t)i * C + 4);
  }

  unsigned short* d0 = dst + eoff + (size_t)c0 * R + r0;
#pragma unroll
  for (int j = 0; j < 8; j++) {
    ushort4 o;
    o.x = f2b(((const float*)&v[0][j >> 2])[j & 3]);
    o.y = f2b(((const float*)&v[1][j >> 2])[j & 3]);
    o.z = f2b(((const float*)&v[2][j >> 2])[j & 3]);
    o.w = f2b(((const float*)&v[3][j >> 2])[j & 3]);
    *(ushort4*)(d0 + (size_t)j * R) = o;
  }
}

// 128x128 tile GEMM, BK=64, bf16 MFMA 16x16x32, global_load_lds width-16 staging.
// 1D grid, XCD-chunked: xcd = id&7 owns tiles [xcd*TPX, xcd*TPX+TPX).
// PHASE 1: A = xb gathered via tok[slot]; silu -> Hout bf16 [slot][NDIM]
// PHASE 2: A = hbuf rows by slot, split-K=2; raw bf16 -> Yout[kh][slot][NDIM]
template <int KLEN, int ASTR, int BSTR, int NDIM, int PHASE>
__global__ __launch_bounds__(256) void moe_gemm_k(
    const unsigned short* __restrict__ Amat, const unsigned short* __restrict__ Bt,
    const int* __restrict__ desc, const int* __restrict__ ntiles_p,
    const int* __restrict__ tok, unsigned short* __restrict__ Hout) {
  int id = blockIdx.x;
  int xcd = id & 7, r = id >> 3;
  int ti = xcd * TPX + r % TPX;
  int q = r / TPX;
  int nb, kh;
  if (PHASE == 1) { nb = q; kh = 0; }
  else           { kh = q & 1; nb = q >> 1; }
  if (ti >= *ntiles_p) return;
  int e = desc[2 * ti];
  int slot0 = desc[2 * ti + 1];

  const unsigned short* Bbase = Bt + (size_t)e * NDIM * BSTR + (size_t)nb * 128 * BSTR + kh * KLEN;

  __shared__ unsigned short As[128 * 64];
  __shared__ unsigned short Bs[128 * 64];

  int tid = threadIdx.x;
  int lane = tid & 63;
  int wave = tid >> 6;
  int wm = (wave >> 1) * 64, wn = (wave & 1) * 64;
  int l15 = lane & 15, quad = lane >> 4;

  f32x4 acc[4][4] = {};

  int sr = tid >> 3;                               // row base, 0..31
  int ldoff = (((lane & 7) ^ (lane >> 3)) * 8);    // content-chunk offset (swizzle inverse)

  const unsigned short* arow[4];
  const unsigned short* brow[4];
#pragma unroll
  for (int p = 0; p < 4; p++) {
    int rr = sr + p * 32;
    int row = (PHASE == 1) ? tok[slot0 + rr] : (slot0 + rr);
    arow[p] = Amat + (size_t)row * ASTR + kh * KLEN + ldoff;
    brow[p] = Bbase + (size_t)rr * BSTR + ldoff;
  }

  for (int kt = 0; kt < KLEN / 64; kt++) {
    int k0 = kt * 64;
#pragma unroll
    for (int p = 0; p < 4; p++) {
      unsigned short* adst = As + (size_t)(p * 256 + wave * 64) * 8;
      unsigned short* bdst = Bs + (size_t)(p * 256 + wave * 64) * 8;
      async16(arow[p] + k0, adst);
      async16(brow[p] + k0, bdst);
    }
    __syncthreads();
#pragma unroll
    for (int ks = 0; ks < 2; ks++) {
      bf16x8 af[4], bfr[4];
#pragma unroll
      for (int i = 0; i < 4; i++) {
        int rr = wm + i * 16 + l15;
        int cc = (((ks * 4 + quad) ^ (rr & 7)) * 8);
        af[i] = *(const bf16x8*)&As[rr * 64 + cc];
      }
#pragma unroll
      for (int j = 0; j < 4; j++) {
        int rr = wn + j * 16 + l15;
        int cc = (((ks * 4 + quad) ^ (rr & 7)) * 8);
        bfr[j] = *(const bf16x8*)&Bs[rr * 64 + cc];
      }
#pragma unroll
      for (int i = 0; i < 4; i++)
#pragma unroll
        for (int j = 0; j < 4; j++)
          acc[i][j] = __builtin_amdgcn_mfma_f32_16x16x32_bf16(af[i], bfr[j], acc[i][j], 0, 0, 0);
    }
    __syncthreads();
  }

  // Epilogue. C/D frag: col = lane&15, row = quad*4 + reg  [verified m89/m91]
#pragma unroll
  for (int i = 0; i < 4; i++) {
    int slotr = slot0 + wm + i * 16 + quad * 4;
#pragma unroll
    for (int rg = 0; rg < 4; rg++) {
      int row = slotr + rg;
      size_t base = (PHASE == 1) ? (size_t)row * NDIM
                                 : ((size_t)kh * MAXPAD + row) * NDIM;
#pragma unroll
      for (int j = 0; j < 4; j++) {
        int col = nb * 128 + wn + j * 16 + l15;
        float v = acc[i][j][rg];
        if (PHASE == 1) v = v / (1.f + __expf(-v));        // silu
        Hout[base + col] = f2b(v);
      }
    }
  }
}

// out[t][d] = sum_k rw[t*2+k] * (y0[slot_of[t*2+k]][d] + y1[slot_of[t*2+k]][d])
__global__ void combine_k(const unsigned short* __restrict__ y, const float* __restrict__ rw,
                          const int* __restrict__ slot_of, float* __restrict__ out) {
  int g = blockIdx.x * blockDim.x + threadIdx.x;   // T*128 threads, 8 elems each
  int t = g >> 7, dd = (g & 127) * 8;
  int s0 = slot_of[2 * t], s1 = slot_of[2 * t + 1];
  float w0 = rw[2 * t], w1 = rw[2 * t + 1];
  const unsigned short* p00 = y + (size_t)s0 * D_DIM + dd;
  const unsigned short* p01 = y + ((size_t)MAXPAD + s0) * D_DIM + dd;
  const unsigned short* p10 = y + (size_t)s1 * D_DIM + dd;
  const unsigned short* p11 = y + ((size_t)MAXPAD + s1) * D_DIM + dd;
  ushort4 a0 = *(const ushort4*)p00, a1 = *(const ushort4*)(p00 + 4);
  ushort4 b0 = *(const ushort4*)p01, b1 = *(const ushort4*)(p01 + 4);
  ushort4 c0 = *(const ushort4*)p10, c1 = *(const ushort4*)(p10 + 4);
  ushort4 d0 = *(const ushort4*)p11, d1 = *(const ushort4*)(p11 + 4);
  float4 o0, o1;
  o0.x = w0 * (b2f(a0.x) + b2f(b0.x)) + w1 * (b2f(c0.x) + b2f(d0.x));
  o0.y = w0 * (b2f(a0.y) + b2f(b0.y)) + w1 * (b2f(c0.y) + b2f(d0.y));
  o0.z = w0 * (b2f(a0.z) + b2f(b0.z)) + w1 * (b2f(c0.z) + b2f(d0.z));
  o0.w = w0 * (b2f(a0.w) + b2f(b0.w)) + w1 * (b2f(c0.w) + b2f(d0.w));
  o1.x = w0 * (b2f(a1.x) + b2f(b1.x)) + w1 * (b2f(c1.x) + b2f(d1.x));
  o1.y = w0 * (b2f(a1.y) + b2f(b1.y)) + w1 * (b2f(c1.y) + b2f(d1.y));
  o1.z = w0 * (b2f(a1.z) + b2f(b1.z)) + w1 * (b2f(c1.z) + b2f(d1.z));
  o1.w = w0 * (b2f(a1.w) + b2f(b1.w)) + w1 * (b2f(c1.w) + b2f(d1.w));
  float* op = out + (size_t)t * D_DIM + dd;
  *(float4*)op = o0;
  *(float4*)(op + 4) = o1;
}

extern "C" void kernel_launch(void* const* d_in, const int* in_sizes, int n_in,
                              void* d_out, int out_size, void* d_ws, size_t ws_size,
                              hipStream_t stream) {
  (void)in_sizes; (void)n_in; (void)ws_size; (void)out_size;
  const float* x  = (const float*)d_in[0];
  const float* rw = (const float*)d_in[1];
  const int*   se = (const int*)d_in[2];
  const float* w1 = (const float*)d_in[3];
  const float* w2 = (const float*)d_in[4];
  float* out = (float*)d_out;
  char* ws = (char*)d_ws;

  int* ntiles  = (int*)(ws + 128);
  int* desc    = (int*)(ws + 256);
  int* tok     = (int*)(ws + 4096);          // MAXPAD ints -> ends 40960
  int* slot_of = (int*)(ws + 40960);         // NSLOTS ints -> ends 73728
  unsigned short* xb   = (unsigned short*)(ws + 131072);              // 8.39 MB
  unsigned short* w1t  = xb + (size_t)T_TOKENS * D_DIM;               // 33.55 MB
  unsigned short* w2t  = w1t + (size_t)E_EXPERTS * D_DIM * I_DIM;     // 33.55 MB
  unsigned short* hbuf = w2t + (size_t)E_EXPERTS * D_DIM * I_DIM;     // 37.75 MB
  // ypart overlays xb+w1t (both dead after phase 1): 37.75 MB <= 41.94 MB
  unsigned short* ypart = xb;

  prep_k<<<PREP_GRID, 256, 0, stream>>>(x, w1, w2, se, xb, w1t, w2t,
                                        ntiles, desc, tok, slot_of);
  // Phase 1: [slots x 1024] @ w1t -> hbuf [slots x 2048];  grid 1152
  moe_gemm_k<1024, 1024, 1024, I_DIM, 1><<<8 * TPX * (I_DIM / 128), 256, 0, stream>>>(
      xb, w1t, desc, ntiles, tok, hbuf);
  // Phase 2: [slots x 2048] @ w2t -> ypart, split-K=2;     grid 1152
  moe_gemm_k<1024, 2048, 2048, D_DIM, 2><<<8 * TPX * (D_DIM / 128) * 2, 256, 0, stream>>>(
      hbuf, w2t, desc, ntiles, tok, ypart);

  combine_k<<<T_TOKENS * 128 / 256, 256, 0, stream>>>(ypart, rw, slot_of, out);
}

// Round 3
// 294.468 us; speedup vs baseline: 1.0049x; 1.0049x over previous
//
#include <hip/hip_runtime.h>
#include <stdint.h>

// Problem constants (fixed by the reference)
#define E_EXPERTS 8
#define D_DIM 1024
#define I_DIM 2048
#define T_TOKENS 4096
#define NSLOTS 8192                 // T * K
#define TILE 128
#define MAXPAD (NSLOTS + E_EXPERTS * TILE)   // 9216
#define TPX 9                       // tiles per XCD chunk (8*9=72 >= max 71 tiles)

// prep grid: 1 routing + 2048 x-cvt + 2048 w1-pack + 2048 w2-pack
#define XCVT_BLOCKS 2048
#define PREP_GRID (1 + XCVT_BLOCKS + 4096)

typedef __attribute__((ext_vector_type(8))) short bf16x8;
typedef __attribute__((ext_vector_type(4))) float f32x4;

__device__ __forceinline__ unsigned short f2b(float f) {
  union { float f; uint32_t u; } v; v.f = f;
  uint32_t r = v.u + 0x7FFFu + ((v.u >> 16) & 1u);   // round-to-nearest-even
  return (unsigned short)(r >> 16);
}
__device__ __forceinline__ float b2f(unsigned short u) {
  union { uint32_t u; float f; } v; v.u = ((uint32_t)u) << 16; return v.f;
}

// async 16B global -> LDS (dest = wave-uniform base + lane*16)
__device__ __forceinline__ void async16(const unsigned short* g, unsigned short* l) {
  __builtin_amdgcn_global_load_lds(
      (const __attribute__((address_space(1))) void*)g,
      (__attribute__((address_space(3))) void*)l, 16, 0, 0);
}

// ---------------- fused prep ----------------
// block 0                 : routing (count -> scan -> pad-fill + scatter)
// blocks [1, 1+2048)      : x fp32 -> bf16, 8 elems/thread
// blocks [1+2048, 1+4096) : w1 -> packed-tile bf16 (see below)
// blocks [1+4096, 1+6144) : w2 -> packed-tile bf16
//
// Packed-tile layout: for (e, nt, kt) the 16KB block holds EXACTLY the byte
// image moe_gemm_k wants in LDS Bs for that (expert, n-tile-128, k-tile-64):
//   elem (rr*8 + cc8)*8 + t  =  w[e][kt*64 + (cc8^(rr&7))*8 + t][nt*128 + rr]
// (the XOR pre-swizzle that was previously applied at GEMM staging-read time).
// prep writes each block as ONE contiguous 16KB region (4KB contiguous per
// store instruction) -> sequential HBM write stream, vs the old 2-4KB-strided
// 64-256B runs that capped prep at ~1.9 TB/s.
// Transpose goes through a 64x129-padded fp32 LDS tile; transposed reads are
// bank-conflict-free: bank = ((c*8+t)*129 + rr) % 32 = (c*8 + t + rr) % 32,
// and within a store group rr spans 64 consecutive values -> 32 banks x 2-way.
__global__ __launch_bounds__(256) void prep_k(
    const float* __restrict__ x, const float* __restrict__ w1, const float* __restrict__ w2,
    const int* __restrict__ se,
    unsigned short* __restrict__ xb, unsigned short* __restrict__ w1t,
    unsigned short* __restrict__ w2t,
    int* __restrict__ ntiles, int* __restrict__ desc,
    int* __restrict__ tok, int* __restrict__ slot_of) {
  int b = blockIdx.x;
  int tid = threadIdx.x;

  if (b == 0) {
    // ---- single-workgroup routing ----
    __shared__ int scnt[E_EXPERTS], sbase[E_EXPERTS + 1], scur[E_EXPERTS];
    if (tid < E_EXPERTS) scnt[tid] = 0;
    __syncthreads();
    for (int s = tid; s < NSLOTS; s += 256) atomicAdd(&scnt[se[s]], 1);
    __syncthreads();
    if (tid == 0) {
      int acc = 0, nt = 0;
      for (int e = 0; e < E_EXPERTS; e++) {
        int n = scnt[e];
        sbase[e] = acc;
        scur[e] = acc;
        int pad = (n + TILE - 1) & ~(TILE - 1);
        for (int m = 0; m * TILE < pad; m++) { desc[2 * nt] = e; desc[2 * nt + 1] = acc + m * TILE; nt++; }
        acc += pad;
      }
      sbase[E_EXPERTS] = acc;
      *ntiles = nt;
    }
    __syncthreads();
    // pad slots -> token 0 (weight is never read for pads; rows are discarded)
    for (int e = 0; e < E_EXPERTS; e++) {
      int s0 = sbase[e] + scnt[e], s1 = sbase[e + 1];
      for (int s = s0 + tid; s < s1; s += 256) tok[s] = 0;
    }
    // scatter (disjoint from pad range)
    for (int s = tid; s < NSLOTS; s += 256) {
      int e = se[s];
      int pos = atomicAdd(&scur[e], 1);
      tok[pos] = s >> 1;      // K=2
      slot_of[s] = pos;
    }
    return;
  }

  int bb = b - 1;

  if (bb < XCVT_BLOCKS) {
    // ---- x fp32 -> bf16, 8 elems/thread ----
    size_t i = ((size_t)bb * 256 + tid) * 8;
    float4 v0 = *(const float4*)(x + i);
    float4 v1 = *(const float4*)(x + i + 4);
    ushort4 o0, o1;
    o0.x = f2b(v0.x); o0.y = f2b(v0.y); o0.z = f2b(v0.z); o0.w = f2b(v0.w);
    o1.x = f2b(v1.x); o1.y = f2b(v1.y); o1.z = f2b(v1.z); o1.w = f2b(v1.w);
    *(ushort4*)(xb + i) = o0;
    *(ushort4*)(xb + i + 4) = o1;
    return;
  }

  // ---- packed-tile transpose-cvt ----
  __shared__ float ts[64 * 129];
  int wb = bb - XCVT_BLOCKS;         // 0..4095
  int mat = wb >> 11;                // 0: w1, 1: w2
  int sub = wb & 2047;
  int e = sub >> 8, rem = sub & 255;
  const float* src; unsigned short* dst; int C, k0, n0;
  if (mat == 0) {                    // w1 [D=K=1024][I=N=2048]: 16 nt x 16 kt
    int nt = rem >> 4, kt = rem & 15;
    C = I_DIM; k0 = kt * 64; n0 = nt * 128;
    src = w1 + (size_t)e * D_DIM * I_DIM;
    dst = w1t + ((size_t)((e * 16 + nt) * 16 + kt)) * 8192;
  } else {                           // w2 [I=K=2048][D=N=1024]: 8 nt x 32 kt
    int nt = rem >> 5, kt = rem & 31;
    C = D_DIM; k0 = kt * 64; n0 = nt * 128;
    src = w2 + (size_t)e * D_DIM * I_DIM;
    dst = w2t + ((size_t)((e * 8 + nt) * 32 + kt)) * 8192;
  }

  // load 64(k) x 128(n) fp32 tile, fully coalesced (8 rows x 512B per instr)
#pragma unroll
  for (int i = 0; i < 8; i++) {
    int f4 = i * 256 + tid;
    int row = f4 >> 5, c4 = (f4 & 31) * 4;
    float4 v = *(const float4*)(src + (size_t)(k0 + row) * C + n0 + c4);
    float* d = ts + row * 129 + c4;
    d[0] = v.x; d[1] = v.y; d[2] = v.z; d[3] = v.w;
  }
  __syncthreads();
  // emit packed chunks; per instruction the 256 threads write 4KB contiguous
#pragma unroll
  for (int j = 0; j < 4; j++) {
    int q = j * 256 + tid;
    int rr = q >> 3, cc8 = q & 7;
    int c = cc8 ^ (rr & 7);
    bf16x8 o;
#pragma unroll
    for (int t = 0; t < 8; t++)
      o[t] = (short)f2b(ts[(c * 8 + t) * 129 + rr]);
    *(bf16x8*)(dst + (size_t)q * 8) = o;
  }
}

// 128x128 tile GEMM, BK=64, bf16 MFMA 16x16x32, global_load_lds width-16 staging.
// 1D grid, XCD-chunked: xcd = id&7 owns tiles [xcd*TPX, xcd*TPX+TPX).
// B is consumed from the packed-tile layout: per kt one contiguous 16KB block
// copied linearly into Bs (byte-identical image to the old swizzled staging).
// PHASE 1: A = xb gathered via tok[slot]; silu -> Hout bf16 [slot][NDIM]
// PHASE 2: A = hbuf rows by slot, split-K=2; raw bf16 -> Yout[kh][slot][NDIM]
template <int KLEN, int KFULL, int NDIM, int PHASE>
__global__ __launch_bounds__(256) void moe_gemm_k(
    const unsigned short* __restrict__ Amat, const unsigned short* __restrict__ Bt,
    const int* __restrict__ desc, const int* __restrict__ ntiles_p,
    const int* __restrict__ tok, unsigned short* __restrict__ Hout) {
  int id = blockIdx.x;
  int xcd = id & 7, r = id >> 3;
  int ti = xcd * TPX + r % TPX;
  int q = r / TPX;
  int nb, kh;
  if (PHASE == 1) { nb = q; kh = 0; }
  else           { kh = q & 1; nb = q >> 1; }
  if (ti >= *ntiles_p) return;
  int e = desc[2 * ti];
  int slot0 = desc[2 * ti + 1];

  __shared__ unsigned short As[128 * 64];
  __shared__ unsigned short Bs[128 * 64];

  int tid = threadIdx.x;
  int lane = tid & 63;
  int wave = tid >> 6;
  int wm = (wave >> 1) * 64, wn = (wave & 1) * 64;
  int l15 = lane & 15, quad = lane >> 4;

  f32x4 acc[4][4] = {};

  int sr = tid >> 3;                               // row base, 0..31
  int ldoff = (((lane & 7) ^ (lane >> 3)) * 8);    // content-chunk offset (swizzle inverse)

  // A: per-row gathered, pre-swizzled global source (LDS dest linear)
  const unsigned short* arow[4];
#pragma unroll
  for (int p = 0; p < 4; p++) {
    int rr = sr + p * 32;
    int row = (PHASE == 1) ? tok[slot0 + rr] : (slot0 + rr);
    arow[p] = Amat + (size_t)row * KFULL + kh * KLEN + ldoff;
  }
  // B: packed tiles, pure sequential copy
  const unsigned short* Bpack =
      Bt + ((((size_t)e * (NDIM / 128) + nb) * (KFULL / 64) + (size_t)kh * (KLEN / 64)) << 13) +
      (size_t)tid * 8;

  for (int kt = 0; kt < KLEN / 64; kt++) {
    int k0 = kt * 64;
#pragma unroll
    for (int p = 0; p < 4; p++) {
      unsigned short* adst = As + (size_t)(p * 256 + wave * 64) * 8;
      unsigned short* bdst = Bs + (size_t)(p * 256 + wave * 64) * 8;
      async16(arow[p] + k0, adst);
      async16(Bpack + (size_t)kt * 8192 + p * 2048, bdst);
    }
    __syncthreads();
#pragma unroll
    for (int ks = 0; ks < 2; ks++) {
      bf16x8 af[4], bfr[4];
#pragma unroll
      for (int i = 0; i < 4; i++) {
        int rr = wm + i * 16 + l15;
        int cc = (((ks * 4 + quad) ^ (rr & 7)) * 8);
        af[i] = *(const bf16x8*)&As[rr * 64 + cc];
      }
#pragma unroll
      for (int j = 0; j < 4; j++) {
        int rr = wn + j * 16 + l15;
        int cc = (((ks * 4 + quad) ^ (rr & 7)) * 8);
        bfr[j] = *(const bf16x8*)&Bs[rr * 64 + cc];
      }
#pragma unroll
      for (int i = 0; i < 4; i++)
#pragma unroll
        for (int j = 0; j < 4; j++)
          acc[i][j] = __builtin_amdgcn_mfma_f32_16x16x32_bf16(af[i], bfr[j], acc[i][j], 0, 0, 0);
    }
    __syncthreads();
  }

  // Epilogue. C/D frag: col = lane&15, row = quad*4 + reg  [verified m89/m91]
#pragma unroll
  for (int i = 0; i < 4; i++) {
    int slotr = slot0 + wm + i * 16 + quad * 4;
#pragma unroll
    for (int rg = 0; rg < 4; rg++) {
      int row = slotr + rg;
      size_t base = (PHASE == 1) ? (size_t)row * NDIM
                                 : ((size_t)kh * MAXPAD + row) * NDIM;
#pragma unroll
      for (int j = 0; j < 4; j++) {
        int col = nb * 128 + wn + j * 16 + l15;
        float v = acc[i][j][rg];
        if (PHASE == 1) v = v / (1.f + __expf(-v));        // silu
        Hout[base + col] = f2b(v);
      }
    }
  }
}

// out[t][d] = sum_k rw[t*2+k] * (y0[slot_of[t*2+k]][d] + y1[slot_of[t*2+k]][d])
__global__ void combine_k(const unsigned short* __restrict__ y, const float* __restrict__ rw,
                          const int* __restrict__ slot_of, float* __restrict__ out) {
  int g = blockIdx.x * blockDim.x + threadIdx.x;   // T*128 threads, 8 elems each
  int t = g >> 7, dd = (g & 127) * 8;
  int s0 = slot_of[2 * t], s1 = slot_of[2 * t + 1];
  float w0 = rw[2 * t], w1 = rw[2 * t + 1];
  const unsigned short* p00 = y + (size_t)s0 * D_DIM + dd;
  const unsigned short* p01 = y + ((size_t)MAXPAD + s0) * D_DIM + dd;
  const unsigned short* p10 = y + (size_t)s1 * D_DIM + dd;
  const unsigned short* p11 = y + ((size_t)MAXPAD + s1) * D_DIM + dd;
  ushort4 a0 = *(const ushort4*)p00, a1 = *(const ushort4*)(p00 + 4);
  ushort4 b0 = *(const ushort4*)p01, b1 = *(const ushort4*)(p01 + 4);
  ushort4 c0 = *(const ushort4*)p10, c1 = *(const ushort4*)(p10 + 4);
  ushort4 d0 = *(const ushort4*)p11, d1 = *(const ushort4*)(p11 + 4);
  float4 o0, o1;
  o0.x = w0 * (b2f(a0.x) + b2f(b0.x)) + w1 * (b2f(c0.x) + b2f(d0.x));
  o0.y = w0 * (b2f(a0.y) + b2f(b0.y)) + w1 * (b2f(c0.y) + b2f(d0.y));
  o0.z = w0 * (b2f(a0.z) + b2f(b0.z)) + w1 * (b2f(c0.z) + b2f(d0.z));
  o0.w = w0 * (b2f(a0.w) + b2f(b0.w)) + w1 * (b2f(c0.w) + b2f(d0.w));
  o1.x = w0 * (b2f(a1.x) + b2f(b1.x)) + w1 * (b2f(c1.x) + b2f(d1.x));
  o1.y = w0 * (b2f(a1.y) + b2f(b1.y)) + w1 * (b2f(c1.y) + b2f(d1.y));
  o1.z = w0 * (b2f(a1.z) + b2f(b1.z)) + w1 * (b2f(c1.z) + b2f(d1.z));
  o1.w = w0 * (b2f(a1.w) + b2f(b1.w)) + w1 * (b2f(c1.w) + b2f(d1.w));
  float* op = out + (size_t)t * D_DIM + dd;
  *(float4*)op = o0;
  *(float4*)(op + 4) = o1;
}

extern "C" void kernel_launch(void* const* d_in, const int* in_sizes, int n_in,
                              void* d_out, int out_size, void* d_ws, size_t ws_size,
                              hipStream_t stream) {
  (void)in_sizes; (void)n_in; (void)ws_size; (void)out_size;
  const float* x  = (const float*)d_in[0];
  const float* rw = (const float*)d_in[1];
  const int*   se = (const int*)d_in[2];
  const float* w1 = (const float*)d_in[3];
  const float* w2 = (const float*)d_in[4];
  float* out = (float*)d_out;
  char* ws = (char*)d_ws;

  int* ntiles  = (int*)(ws + 128);
  int* desc    = (int*)(ws + 256);
  int* tok     = (int*)(ws + 4096);          // MAXPAD ints -> ends 40960
  int* slot_of = (int*)(ws + 40960);         // NSLOTS ints -> ends 73728
  unsigned short* xb   = (unsigned short*)(ws + 131072);              // 8.39 MB
  unsigned short* w1t  = xb + (size_t)T_TOKENS * D_DIM;               // 33.55 MB (packed tiles)
  unsigned short* w2t  = w1t + (size_t)E_EXPERTS * D_DIM * I_DIM;     // 33.55 MB (packed tiles)
  unsigned short* hbuf = w2t + (size_t)E_EXPERTS * D_DIM * I_DIM;     // 37.75 MB
  // ypart overlays xb+w1t (both dead after phase 1): 37.75 MB <= 41.94 MB
  unsigned short* ypart = xb;

  prep_k<<<PREP_GRID, 256, 0, stream>>>(x, w1, w2, se, xb, w1t, w2t,
                                        ntiles, desc, tok, slot_of);
  // Phase 1: [slots x 1024] @ w1t(packed) -> hbuf [slots x 2048];  grid 1152
  moe_gemm_k<1024, 1024, I_DIM, 1><<<8 * TPX * (I_DIM / 128), 256, 0, stream>>>(
      xb, w1t, desc, ntiles, tok, hbuf);
  // Phase 2: [slots x 2048] @ w2t(packed) -> ypart, split-K=2;     grid 1152
  moe_gemm_k<1024, 2048, D_DIM, 2><<<8 * TPX * (D_DIM / 128) * 2, 256, 0, stream>>>(
      hbuf, w2t, desc, ntiles, tok, ypart);

  combine_k<<<T_TOKENS * 128 / 256, 256, 0, stream>>>(ypart, rw, slot_of, out);
}